// Round 7
// baseline (304.401 us; speedup 1.0000x reference)
//
#include <hip/hip_runtime.h>
#include <hip/hip_bf16.h>
#include <stdint.h>

typedef __hip_bfloat16 bf16;
typedef __attribute__((ext_vector_type(8))) short short8;   // 8 x bf16 = 16B
typedef __attribute__((ext_vector_type(4))) float float4v;

#define MFMA16(a, b, c) __builtin_amdgcn_mfma_f32_16x16x32_bf16((a), (b), (c), 0, 0, 0)

static __device__ __forceinline__ short f2bf(float f) {
    bf16 h = __float2bfloat16(f);
    return *reinterpret_cast<short*>(&h);
}

// async global->LDS, 16B per lane; dest = lds_base + lane*16 (wave-uniform base)
static __device__ __forceinline__ void gl2lds16(const void* g, void* l) {
    __builtin_amdgcn_global_load_lds(
        (const __attribute__((address_space(1))) void*)g,
        (__attribute__((address_space(3))) void*)l, 16, 0, 0);
}

// =====================================================================
// Fused f32 -> bf16 convert for all three tensors (one launch).
// Each thread converts 8 elements; ranges are multiples of 8.
// =====================================================================
__global__ __launch_bounds__(256) void cvt_all(
    const float* __restrict__ a, bf16* __restrict__ A, int na,
    const float* __restrict__ b, bf16* __restrict__ B, int nb,
    const float* __restrict__ c, bf16* __restrict__ C, int nc)
{
    int i = (blockIdx.x * 256 + threadIdx.x) * 8;
    const float* src; bf16* dst;
    if (i < na)            { src = a; dst = A; }
    else if (i < na + nb)  { i -= na; src = b; dst = B; if (i >= nb) return; }
    else                   { i -= na + nb; src = c; dst = C; if (i >= nc) return; }
    const float4v x0 = *(const float4v*)(src + i);
    const float4v x1 = *(const float4v*)(src + i + 4);
    short8 v;
#pragma unroll
    for (int q = 0; q < 4; ++q) { v[q] = f2bf(x0[q]); v[q + 4] = f2bf(x1[q]); }
    *(short8*)(dst + i) = v;
}

// =====================================================================
// GEMM: C[M][N] = X[M][K] @ W[N][K]^T + bias[N]; X,W bf16, bias f32.
// mode 0: store C f32; gridDim.z>1 => split-K atomicAdd (Cout pre-zeroed,
//         bias added by z==0 only).
// mode 1: QKV scatter. Blocks with n0<2304: QK bf16 row-major (scalar).
//         Blocks with n0>=2304 (V): LDS-transpose epilogue -> coalesced
//         16B stores into Vt[h*72+d][tok].
// 128x128 tile, BK=32, dbuf LDS (1 barrier/iter), global_load_lds 16B,
// XOR chunk swizzle (0 bank conflicts verified R5).
// =====================================================================
__global__ __launch_bounds__(256) void gemm_xwt(
    const bf16* __restrict__ X, const bf16* __restrict__ W,
    const float* __restrict__ bias,
    float* __restrict__ Cout,
    bf16* __restrict__ QK, bf16* __restrict__ Vt,
    int M, int N, int K, int mode)
{
    __shared__ __align__(16) bf16 SMEM[16384];   // 32 KB: As[2]|Bs[2], reused as T
    bf16* As = SMEM;            // [2][128*32]
    bf16* Bs = SMEM + 8192;     // [2][128*32]

    const int tid  = threadIdx.x;
    const int wave = tid >> 6;
    const int lane = tid & 63;
    const int quad = lane >> 4;
    const int l16  = lane & 15;
    const int m0 = blockIdx.x * 128;
    const int n0 = blockIdx.y * 128;
    const int wm = (wave >> 1) * 64;
    const int wn = (wave & 1) * 64;

    const int lrow   = lane >> 2;
    const int lchunk = lane & 3;

    const int kper = K / gridDim.z;
    const int kbeg = blockIdx.z * kper;
    const int nIt  = kper >> 5;

    float4v acc[4][4];
    const float4v zf = {0.f, 0.f, 0.f, 0.f};
#pragma unroll
    for (int i = 0; i < 4; ++i)
#pragma unroll
        for (int j = 0; j < 4; ++j) acc[i][j] = zf;

    auto stage = [&](int buf, int k0) {
#pragma unroll
        for (int ii = 0; ii < 2; ++ii) {
            const int rbase = wave * 32 + ii * 16;
            const int r  = rbase + lrow;
            const int sc = lchunk ^ ((r >> 1) & 3);
            gl2lds16(&X[(size_t)(m0 + r) * K + k0 + sc * 8], &As[buf * 4096 + rbase * 32]);
            gl2lds16(&W[(size_t)(n0 + r) * K + k0 + sc * 8], &Bs[buf * 4096 + rbase * 32]);
        }
    };

    stage(0, kbeg);

    for (int it = 0; it < nIt; ++it) {
        __syncthreads();
        if (it + 1 < nIt) stage((it + 1) & 1, kbeg + (it + 1) * 32);

        const int b = it & 1;
        short8 af[4], bfr[4];
#pragma unroll
        for (int i = 0; i < 4; ++i) {
            const int r = wm + i * 16 + l16;
            af[i] = *(const short8*)&As[b * 4096 + r * 32 + (quad ^ ((r >> 1) & 3)) * 8];
        }
#pragma unroll
        for (int j = 0; j < 4; ++j) {
            const int r = wn + j * 16 + l16;
            bfr[j] = *(const short8*)&Bs[b * 4096 + r * 32 + (quad ^ ((r >> 1) & 3)) * 8];
        }
#pragma unroll
        for (int i = 0; i < 4; ++i)
#pragma unroll
            for (int j = 0; j < 4; ++j)
                acc[i][j] = MFMA16(af[i], bfr[j], acc[i][j]);
    }

    // ---------------- epilogue ----------------
    if (mode == 1 && n0 >= 2304) {
        // V region: transpose through LDS, coalesced Vt stores.
        // T is [64 cols][stride 136] bf16 per half (17408 B <= 32 KB).
        bf16* T = SMEM;
#pragma unroll 1
        for (int half = 0; half < 2; ++half) {
            __syncthreads();   // T reuse / staging LDS done
            if ((wave & 1) == half) {
#pragma unroll
                for (int j = 0; j < 4; ++j) {
                    const int col = n0 + wn + j * 16 + l16;
                    const float bb = bias[col];
#pragma unroll
                    for (int i = 0; i < 4; ++i)
#pragma unroll
                        for (int r = 0; r < 4; ++r)
                            T[(j * 16 + l16) * 136 + wm + i * 16 + quad * 4 + r] =
                                __float2bfloat16(acc[i][j][r] + bb);
                }
            }
            __syncthreads();
            // 256 threads store 64 cols x 128 tokens: thread t -> col t>>2,
            // token chunk (t&3)*32, 4 x 16B stores.
            const int dd   = tid >> 2;
            const int tok0 = (tid & 3) * 32;
            const int colg = n0 + half * 64 + dd - 2304;
            const int hh   = colg / 72;
            const int dm   = colg - hh * 72;
            bf16* dst = &Vt[((size_t)hh * 72 + dm) * 4096 + m0 + tok0];
#pragma unroll
            for (int k = 0; k < 4; ++k)
                *(short8*)(dst + k * 8) = *(const short8*)&T[dd * 136 + tok0 + k * 8];
        }
        return;
    }

    const bool split = (gridDim.z > 1);
    const float bscale = (!split || blockIdx.z == 0) ? 1.f : 0.f;
#pragma unroll
    for (int j = 0; j < 4; ++j) {
        const int col = n0 + wn + j * 16 + l16;
        const float bb = bias[col] * bscale;
#pragma unroll
        for (int i = 0; i < 4; ++i) {
#pragma unroll
            for (int r = 0; r < 4; ++r) {
                const int row = m0 + wm + i * 16 + quad * 4 + r;
                const float val = acc[i][j][r] + bb;
                if (mode == 0) {
                    if (split) atomicAdd(&Cout[(size_t)row * N + col], val);
                    else       Cout[(size_t)row * N + col] = val;
                } else {
                    QK[(size_t)row * 2304 + col] = __float2bfloat16(val);
                }
            }
        }
    }
}

// =====================================================================
// Varlen flash attention, BARRIER-FREE:
//  - Q, K, V MFMA fragments all load directly global->VGPR (16B/lane,
//    fragment row = lane&15 / k = quad*8+j matches 16x16x32 A/B layout).
//  - Only P round-trips LDS, per-wave private (wave-local lgkm ordering;
//    no __syncthreads anywhere in the kernel body).
//  - kv tiles 64-aligned; masks handle both seq_start and seq_end.
// Grid: (qblock<=72, head=16). Block 256 = 4 independent waves.
// =====================================================================
__global__ __launch_bounds__(256) void attn_varlen(
    const bf16* __restrict__ QK, const bf16* __restrict__ Vt,
    const int* __restrict__ cu, bf16* __restrict__ AO)
{
    const float scale = 0.11785113019775793f;  // 72^-0.5
    __shared__ __align__(16) bf16 Ps[4][16 * 72];   // per-wave P, stride 72

    const int tid  = threadIdx.x;
    const int wave = tid >> 6;
    const int lane = tid & 63;
    const int quad = lane >> 4;
    const int l16  = lane & 15;
    const int h  = blockIdx.y;
    const int qb = blockIdx.x;

    int seq_end = 0, q0 = -1, accb = 0, seq_start = 0;
    for (int i = 0; i < 8; ++i) {
        const int st = cu[i], en = cu[i + 1];
        const int nb = (en - st + 63) >> 6;
        if (q0 < 0 && qb < accb + nb) {
            seq_start = st; seq_end = en; q0 = st + (qb - accb) * 64;
        }
        accb += nb;
    }
    if (q0 < 0) return;

    const short8 z8 = {0, 0, 0, 0, 0, 0, 0, 0};

    // Q fragments (rows clamped for tail q-blocks; results discarded there)
    int qrow_f = q0 + wave * 16 + l16; if (qrow_f > 4095) qrow_f = 4095;
    const bf16* qp = &QK[(size_t)qrow_f * 2304 + h * 72];
    short8 aq[3];
    aq[0] = *(const short8*)(qp + quad * 8);
    aq[1] = *(const short8*)(qp + 32 + quad * 8);
    aq[2] = (quad == 0) ? *(const short8*)(qp + 64) : z8;

    const float4v zf = {0.f, 0.f, 0.f, 0.f};
    float4v oacc[5];
#pragma unroll
    for (int d = 0; d < 5; ++d) oacc[d] = zf;
    float m_i[4], l_i[4];
#pragma unroll
    for (int r = 0; r < 4; ++r) { m_i[r] = -1.0e30f; l_i[r] = 0.f; }

    // V fragment row indices (loop-invariant), clamped in-bounds:
    // d=4, l16>=8 -> dim>=72 is garbage-but-finite, discarded at store.
    int vrow[5];
#pragma unroll
    for (int d = 0; d < 5; ++d) {
        int vr = h * 72 + d * 16 + l16;
        vrow[d] = (vr > 1151) ? 1151 : vr;
    }

    const int kvbeg = seq_start & ~63;
    for (int kv0 = kvbeg; kv0 < seq_end; kv0 += 64) {
        // K fragments, direct global
        short8 bk[4][3];
#pragma unroll
        for (int nt = 0; nt < 4; ++nt) {
            const bf16* kp = &QK[(size_t)(kv0 + nt * 16 + l16) * 2304 + 1152 + h * 72];
            bk[nt][0] = *(const short8*)(kp + quad * 8);
            bk[nt][1] = *(const short8*)(kp + 32 + quad * 8);
            bk[nt][2] = (quad == 0) ? *(const short8*)(kp + 64) : z8;
        }

        float4v sc[4];
#pragma unroll
        for (int nt = 0; nt < 4; ++nt) {
            float4v s = zf;
#pragma unroll
            for (int kk = 0; kk < 3; ++kk)
                s = MFMA16(aq[kk], bk[nt][kk], s);
            sc[nt] = s;
        }
        // mask both ends + scale
#pragma unroll
        for (int nt = 0; nt < 4; ++nt) {
            const int kv = kv0 + nt * 16 + l16;
            const bool ok = (kv >= seq_start) && (kv < seq_end);
#pragma unroll
            for (int r = 0; r < 4; ++r)
                sc[nt][r] = ok ? sc[nt][r] * scale : -1.0e30f;
        }
        // online softmax: rows at quad*4+reg, cols across the 16-lane group
        float mnew[4], alpha[4];
#pragma unroll
        for (int r = 0; r < 4; ++r) {
            float rm = fmaxf(fmaxf(sc[0][r], sc[1][r]), fmaxf(sc[2][r], sc[3][r]));
            rm = fmaxf(rm, __shfl_xor(rm, 1));
            rm = fmaxf(rm, __shfl_xor(rm, 2));
            rm = fmaxf(rm, __shfl_xor(rm, 4));
            rm = fmaxf(rm, __shfl_xor(rm, 8));
            mnew[r]  = fmaxf(m_i[r], rm);
            alpha[r] = __expf(m_i[r] - mnew[r]);
            m_i[r]   = mnew[r];
        }
        float rs[4] = {0.f, 0.f, 0.f, 0.f};
#pragma unroll
        for (int nt = 0; nt < 4; ++nt)
#pragma unroll
            for (int r = 0; r < 4; ++r) {
                const float p = __expf(sc[nt][r] - mnew[r]);
                sc[nt][r] = p;
                rs[r] += p;
            }
#pragma unroll
        for (int r = 0; r < 4; ++r) {
            rs[r] += __shfl_xor(rs[r], 1);
            rs[r] += __shfl_xor(rs[r], 2);
            rs[r] += __shfl_xor(rs[r], 4);
            rs[r] += __shfl_xor(rs[r], 8);
            l_i[r] = l_i[r] * alpha[r] + rs[r];
        }
#pragma unroll
        for (int d = 0; d < 5; ++d)
#pragma unroll
            for (int r = 0; r < 4; ++r) oacc[d][r] *= alpha[r];

        // P (C-layout) -> per-wave LDS -> A-layout (wave-local, no barrier)
#pragma unroll
        for (int nt = 0; nt < 4; ++nt)
#pragma unroll
            for (int r = 0; r < 4; ++r)
                Ps[wave][(quad * 4 + r) * 72 + nt * 16 + l16] = __float2bfloat16(sc[nt][r]);

        const short8 ap0 = *(const short8*)&Ps[wave][l16 * 72 + quad * 8];
        const short8 ap1 = *(const short8*)&Ps[wave][l16 * 72 + 32 + quad * 8];

        // PV with direct-global V fragments
#pragma unroll
        for (int d = 0; d < 5; ++d) {
            const bf16* vp = &Vt[(size_t)vrow[d] * 4096 + kv0];
            const short8 bv0 = *(const short8*)(vp + quad * 8);
            const short8 bv1 = *(const short8*)(vp + 32 + quad * 8);
            oacc[d] = MFMA16(ap0, bv0, oacc[d]);
            oacc[d] = MFMA16(ap1, bv1, oacc[d]);
        }
    }

    // epilogue: AO[t][h*72+d] = O / l
#pragma unroll
    for (int r = 0; r < 4; ++r) {
        const int qrow = q0 + wave * 16 + quad * 4 + r;
        if (qrow < seq_end) {
            const float inv = (l_i[r] > 0.f) ? (1.0f / l_i[r]) : 0.f;
#pragma unroll
            for (int d = 0; d < 5; ++d) {
                const int dim = d * 16 + l16;
                if (dim < 72)
                    AO[(size_t)qrow * 1152 + h * 72 + dim] =
                        __float2bfloat16(oacc[d][r] * inv);
            }
        }
    }
}

extern "C" void kernel_launch(void* const* d_in, const int* in_sizes, int n_in,
                              void* d_out, int out_size, void* d_ws, size_t ws_size,
                              hipStream_t stream)
{
    const float* Xf   = (const float*)d_in[0];  // [4096][1152]
    const float* Wqkv = (const float*)d_in[1];  // [3456][1152]
    const float* Bqkv = (const float*)d_in[2];  // [3456]
    const float* Wout = (const float*)d_in[3];  // [1152][1152]
    const float* Bout = (const float*)d_in[4];  // [1152]
    const int*   cu   = (const int*)d_in[5];    // [9]

    const size_t X16_B  = (size_t)4096 * 1152 * 2;
    const size_t WQ16_B = (size_t)3456 * 1152 * 2;
    const size_t WO16_B = (size_t)1152 * 1152 * 2;
    const size_t QK_B   = (size_t)4096 * 2304 * 2;
    const size_t VT_B   = (size_t)16 * 72 * 4096 * 2;

    char* ws = (char*)d_ws;
    bf16* X16  = (bf16*)ws;
    bf16* WQ16 = (bf16*)(ws + X16_B);
    bf16* WO16 = (bf16*)(ws + X16_B + WQ16_B);
    bf16* QK   = (bf16*)(ws + X16_B + WQ16_B + WO16_B);
    bf16* Vt   = (bf16*)(ws + X16_B + WQ16_B + WO16_B + QK_B);
    bf16* AO   = (bf16*)(ws + X16_B + WQ16_B + WO16_B + QK_B + VT_B);
    float* Out = (float*)d_out;

    dim3 blk(256);
    // fused f32->bf16 conversions: 10,027,008 elems / 8 / 256 = 4896 blocks
    cvt_all<<<dim3(4896), blk, 0, stream>>>(Xf, X16, 4096 * 1152,
                                            Wqkv, WQ16, 3456 * 1152,
                                            Wout, WO16, 1152 * 1152);

    // zero d_out for split-K atomics
    hipMemsetAsync(d_out, 0, (size_t)4096 * 1152 * 4, stream);

    // QKV projection
    gemm_xwt<<<dim3(32, 27, 1), blk, 0, stream>>>(X16, WQ16, Bqkv, nullptr, QK, Vt,
                                                  4096, 3456, 1152, 1);
    // varlen attention (barrier-free)
    attn_varlen<<<dim3(72, 16), blk, 0, stream>>>(QK, Vt, cu, AO);
    // output projection, split-K=2
    gemm_xwt<<<dim3(32, 9, 2), blk, 0, stream>>>(AO, WO16, Bout, Out, nullptr, nullptr,
                                                 4096, 1152, 1152, 0);
}

// Round 8
// 250.455 us; speedup vs baseline: 1.2154x; 1.2154x over previous
//
#include <hip/hip_runtime.h>
#include <hip/hip_bf16.h>
#include <stdint.h>

typedef __hip_bfloat16 bf16;
typedef __attribute__((ext_vector_type(8))) short short8;   // 8 x bf16 = 16B
typedef __attribute__((ext_vector_type(4))) float float4v;

#define MFMA16(a, b, c) __builtin_amdgcn_mfma_f32_16x16x32_bf16((a), (b), (c), 0, 0, 0)

static __device__ __forceinline__ short f2bf(float f) {
    bf16 h = __float2bfloat16(f);
    return *reinterpret_cast<short*>(&h);
}

// async global->LDS, 16B per lane; dest = lds_base (wave-uniform) + lane*16
static __device__ __forceinline__ void gl2lds16(const void* g, void* l) {
    __builtin_amdgcn_global_load_lds(
        (const __attribute__((address_space(1))) void*)g,
        (__attribute__((address_space(3))) void*)l, 16, 0, 0);
}

// =====================================================================
// Fused f32 -> bf16 convert for all three tensors (one launch).
// =====================================================================
__global__ __launch_bounds__(256) void cvt_all(
    const float* __restrict__ a, bf16* __restrict__ A, int na,
    const float* __restrict__ b, bf16* __restrict__ B, int nb,
    const float* __restrict__ c, bf16* __restrict__ C, int nc)
{
    int i = (blockIdx.x * 256 + threadIdx.x) * 8;
    const float* src; bf16* dst;
    if (i < na)            { src = a; dst = A; }
    else if (i < na + nb)  { i -= na; src = b; dst = B; if (i >= nb) return; }
    else                   { i -= na + nb; src = c; dst = C; if (i >= nc) return; }
    const float4v x0 = *(const float4v*)(src + i);
    const float4v x1 = *(const float4v*)(src + i + 4);
    short8 v;
#pragma unroll
    for (int q = 0; q < 4; ++q) { v[q] = f2bf(x0[q]); v[q + 4] = f2bf(x1[q]); }
    *(short8*)(dst + i) = v;
}

// =====================================================================
// GEMM: C[M][N] = X[M][K] @ W[N][K]^T + bias[N]; X,W bf16, bias f32.
// mode 0: store C f32; gridDim.z>1 => split-K atomicAdd.
// mode 1: QKV scatter into per-head layouts:
//   col<1152        -> Qh[h][row][d]   (h=col/72, d=col%72)
//   1152<=col<2304  -> Kh[h][row][d]
//   col>=2304       -> Vt[h][d][tok] via LDS-transpose (coalesced 16B stores)
// 128x128 tile, BK=32, dbuf LDS (1 barrier/iter), global_load_lds 16B,
// XOR chunk swizzle (0 bank conflicts verified R5).
// =====================================================================
__global__ __launch_bounds__(256) void gemm_xwt(
    const bf16* __restrict__ X, const bf16* __restrict__ W,
    const float* __restrict__ bias,
    float* __restrict__ Cout,
    bf16* __restrict__ Qh, bf16* __restrict__ Kh, bf16* __restrict__ Vt,
    int M, int N, int K, int mode)
{
    __shared__ __align__(16) bf16 SMEM[16384];   // 32 KB
    bf16* As = SMEM;            // [2][128*32]
    bf16* Bs = SMEM + 8192;

    const int tid  = threadIdx.x;
    const int wave = tid >> 6;
    const int lane = tid & 63;
    const int quad = lane >> 4;
    const int l16  = lane & 15;
    const int m0 = blockIdx.x * 128;
    const int n0 = blockIdx.y * 128;
    const int wm = (wave >> 1) * 64;
    const int wn = (wave & 1) * 64;

    const int lrow   = lane >> 2;
    const int lchunk = lane & 3;

    const int kper = K / gridDim.z;
    const int kbeg = blockIdx.z * kper;
    const int nIt  = kper >> 5;

    float4v acc[4][4];
    const float4v zf = {0.f, 0.f, 0.f, 0.f};
#pragma unroll
    for (int i = 0; i < 4; ++i)
#pragma unroll
        for (int j = 0; j < 4; ++j) acc[i][j] = zf;

    auto stage = [&](int buf, int k0) {
#pragma unroll
        for (int ii = 0; ii < 2; ++ii) {
            const int rbase = wave * 32 + ii * 16;
            const int r  = rbase + lrow;
            const int sc = lchunk ^ ((r >> 1) & 3);
            gl2lds16(&X[(size_t)(m0 + r) * K + k0 + sc * 8], &As[buf * 4096 + rbase * 32]);
            gl2lds16(&W[(size_t)(n0 + r) * K + k0 + sc * 8], &Bs[buf * 4096 + rbase * 32]);
        }
    };

    stage(0, kbeg);

    for (int it = 0; it < nIt; ++it) {
        __syncthreads();
        if (it + 1 < nIt) stage((it + 1) & 1, kbeg + (it + 1) * 32);

        const int b = it & 1;
        short8 af[4], bfr[4];
#pragma unroll
        for (int i = 0; i < 4; ++i) {
            const int r = wm + i * 16 + l16;
            af[i] = *(const short8*)&As[b * 4096 + r * 32 + (quad ^ ((r >> 1) & 3)) * 8];
        }
#pragma unroll
        for (int j = 0; j < 4; ++j) {
            const int r = wn + j * 16 + l16;
            bfr[j] = *(const short8*)&Bs[b * 4096 + r * 32 + (quad ^ ((r >> 1) & 3)) * 8];
        }
#pragma unroll
        for (int i = 0; i < 4; ++i)
#pragma unroll
            for (int j = 0; j < 4; ++j)
                acc[i][j] = MFMA16(af[i], bfr[j], acc[i][j]);
    }

    // ---------------- epilogue ----------------
    if (mode == 1 && n0 >= 2304) {
        // V region: transpose through LDS, coalesced Vt stores.
        bf16* T = SMEM;   // [64][stride 136]
#pragma unroll 1
        for (int half = 0; half < 2; ++half) {
            __syncthreads();
            if ((wave & 1) == half) {
#pragma unroll
                for (int j = 0; j < 4; ++j) {
                    const int col = n0 + wn + j * 16 + l16;
                    const float bb = bias[col];
#pragma unroll
                    for (int i = 0; i < 4; ++i)
#pragma unroll
                        for (int r = 0; r < 4; ++r)
                            T[(j * 16 + l16) * 136 + wm + i * 16 + quad * 4 + r] =
                                __float2bfloat16(acc[i][j][r] + bb);
                }
            }
            __syncthreads();
            const int dd   = tid >> 2;
            const int tok0 = (tid & 3) * 32;
            const int colg = n0 + half * 64 + dd - 2304;
            const int hh   = colg / 72;
            const int dm   = colg - hh * 72;
            bf16* dst = &Vt[((size_t)hh * 72 + dm) * 4096 + m0 + tok0];
#pragma unroll
            for (int k = 0; k < 4; ++k)
                *(short8*)(dst + k * 8) = *(const short8*)&T[dd * 136 + tok0 + k * 8];
        }
        return;
    }

    const bool split = (gridDim.z > 1);
    const float bscale = (!split || blockIdx.z == 0) ? 1.f : 0.f;
#pragma unroll
    for (int j = 0; j < 4; ++j) {
        const int col = n0 + wn + j * 16 + l16;
        const float bb = bias[col] * bscale;
#pragma unroll
        for (int i = 0; i < 4; ++i) {
#pragma unroll
            for (int r = 0; r < 4; ++r) {
                const int row = m0 + wm + i * 16 + quad * 4 + r;
                const float val = acc[i][j][r] + bb;
                if (mode == 0) {
                    if (split) atomicAdd(&Cout[(size_t)row * N + col], val);
                    else       Cout[(size_t)row * N + col] = val;
                } else {
                    const bf16 bv = __float2bfloat16(val);
                    if (col < 1152) {
                        const int hh = col / 72, dd = col - hh * 72;
                        Qh[((size_t)hh * 4096 + row) * 72 + dd] = bv;
                    } else {
                        const int c2 = col - 1152;
                        const int hh = c2 / 72, dd = c2 - hh * 72;
                        Kh[((size_t)hh * 4096 + row) * 72 + dd] = bv;
                    }
                }
            }
        }
    }
}

// =====================================================================
// Varlen flash attention. Grid (qb128, head), block 512 = 8 waves.
// Wave w owns q rows [q0+16w, q0+16w+16). kv tiles of 64, 64-aligned.
// K/V staged once per block via global_load_lds (coalesced, async),
// double-buffered, ONE barrier per kv tile.
//  - Ks[64][72] contiguous (natural 2-way banks).
//  - Vs[72][64] with source-side XOR chunk swizzle (2-way banks).
//  - Q fragments direct-global, loaded once.
//  - P round-trip per-wave LDS (no barrier).
// =====================================================================
__global__ __launch_bounds__(512) void attn_varlen(
    const bf16* __restrict__ Qh, const bf16* __restrict__ Kh,
    const bf16* __restrict__ Vt,
    const int* __restrict__ cu, bf16* __restrict__ AO)
{
    const float scale = 0.11785113019775793f;  // 72^-0.5
    __shared__ __align__(16) bf16 Ks[2][64 * 72];
    __shared__ __align__(16) bf16 Vs[2][72 * 64];
    __shared__ __align__(16) bf16 Ps[8][16 * 72];

    const int tid  = threadIdx.x;
    const int wave = tid >> 6;
    const int lane = tid & 63;
    const int quad = lane >> 4;
    const int l16  = lane & 15;
    const int h  = blockIdx.y;
    const int qb = blockIdx.x;

    int seq_end = 0, q0 = -1, accb = 0, seq_start = 0;
    for (int i = 0; i < 8; ++i) {
        const int st = cu[i], en = cu[i + 1];
        const int nb = (en - st + 127) >> 7;
        if (q0 < 0 && qb < accb + nb) {
            seq_start = st; seq_end = en; q0 = st + (qb - accb) * 128;
        }
        accb += nb;
    }
    if (q0 < 0) return;   // uniform across block

    const short8 z8 = {0, 0, 0, 0, 0, 0, 0, 0};

    // Q fragments, direct global, once (tail rows clamped; discarded at store)
    int qrow_f = q0 + wave * 16 + l16; if (qrow_f > 4095) qrow_f = 4095;
    const bf16* qp = &Qh[((size_t)h * 4096 + qrow_f) * 72];
    short8 aq[3];
    aq[0] = *(const short8*)(qp + quad * 8);
    aq[1] = *(const short8*)(qp + 32 + quad * 8);
    aq[2] = (quad == 0) ? *(const short8*)(qp + 64) : z8;

    // stage one kv tile (64 toks) into buffer `buf`
    const bf16* kbase = &Kh[(size_t)h * 4096 * 72];
    auto stage = [&](int buf, int kv0) {
        const bf16* ksrc = kbase + (size_t)kv0 * 72;   // contiguous 9216 B
#pragma unroll
        for (int i = wave; i < 9; i += 8)
            gl2lds16(ksrc + i * 512 + lane * 8, &Ks[buf][i * 512]);
#pragma unroll
        for (int i = wave; i < 9; i += 8) {
            const int d  = i * 8 + (lane >> 3);
            const int ch = (lane & 7) ^ (d & 7);   // source-side swizzle
            gl2lds16(&Vt[((size_t)h * 72 + d) * 4096 + kv0 + ch * 8],
                     &Vs[buf][i * 512]);
        }
    };

    const float4v zf = {0.f, 0.f, 0.f, 0.f};
    float4v oacc[5];
#pragma unroll
    for (int d = 0; d < 5; ++d) oacc[d] = zf;
    float m_i[4], l_i[4];
#pragma unroll
    for (int r = 0; r < 4; ++r) { m_i[r] = -1.0e30f; l_i[r] = 0.f; }

    const int kvbeg = seq_start & ~63;
    stage(0, kvbeg);

    for (int kv0 = kvbeg; kv0 < seq_end; kv0 += 64) {
        const int b = ((kv0 - kvbeg) >> 6) & 1;
        __syncthreads();   // prior tile's reads done; this wave's prefetch drains
        if (kv0 + 64 < seq_end) stage(b ^ 1, kv0 + 64);

        // S = Q K^T (K frags from LDS, stride 72 = 2-way banks)
        float4v sc[4];
#pragma unroll
        for (int nt = 0; nt < 4; ++nt) {
            const bf16* kb = &Ks[b][(nt * 16 + l16) * 72];
            float4v s = zf;
            s = MFMA16(aq[0], *(const short8*)(kb + quad * 8), s);
            s = MFMA16(aq[1], *(const short8*)(kb + 32 + quad * 8), s);
            s = MFMA16(aq[2], (quad == 0) ? *(const short8*)(kb + 64) : z8, s);
            sc[nt] = s;
        }
        // mask both ends + scale
#pragma unroll
        for (int nt = 0; nt < 4; ++nt) {
            const int kv = kv0 + nt * 16 + l16;
            const bool ok = (kv >= seq_start) && (kv < seq_end);
#pragma unroll
            for (int r = 0; r < 4; ++r)
                sc[nt][r] = ok ? sc[nt][r] * scale : -1.0e30f;
        }
        // online softmax (rows at quad*4+reg, cols across 16-lane group)
        float mnew[4], alpha[4];
#pragma unroll
        for (int r = 0; r < 4; ++r) {
            float rm = fmaxf(fmaxf(sc[0][r], sc[1][r]), fmaxf(sc[2][r], sc[3][r]));
            rm = fmaxf(rm, __shfl_xor(rm, 1));
            rm = fmaxf(rm, __shfl_xor(rm, 2));
            rm = fmaxf(rm, __shfl_xor(rm, 4));
            rm = fmaxf(rm, __shfl_xor(rm, 8));
            mnew[r]  = fmaxf(m_i[r], rm);
            alpha[r] = __expf(m_i[r] - mnew[r]);
            m_i[r]   = mnew[r];
        }
        float rs[4] = {0.f, 0.f, 0.f, 0.f};
#pragma unroll
        for (int nt = 0; nt < 4; ++nt)
#pragma unroll
            for (int r = 0; r < 4; ++r) {
                const float p = __expf(sc[nt][r] - mnew[r]);
                sc[nt][r] = p;
                rs[r] += p;
            }
#pragma unroll
        for (int r = 0; r < 4; ++r) {
            rs[r] += __shfl_xor(rs[r], 1);
            rs[r] += __shfl_xor(rs[r], 2);
            rs[r] += __shfl_xor(rs[r], 4);
            rs[r] += __shfl_xor(rs[r], 8);
            l_i[r] = l_i[r] * alpha[r] + rs[r];
        }
#pragma unroll
        for (int d = 0; d < 5; ++d)
#pragma unroll
            for (int r = 0; r < 4; ++r) oacc[d][r] *= alpha[r];

        // P (C-layout) -> per-wave LDS -> A-layout (wave-local ordering)
#pragma unroll
        for (int nt = 0; nt < 4; ++nt)
#pragma unroll
            for (int r = 0; r < 4; ++r)
                Ps[wave][(quad * 4 + r) * 72 + nt * 16 + l16] = __float2bfloat16(sc[nt][r]);

        const short8 ap0 = *(const short8*)&Ps[wave][l16 * 72 + quad * 8];
        const short8 ap1 = *(const short8*)&Ps[wave][l16 * 72 + 32 + quad * 8];

        // PV (V frags from LDS, swizzled chunks = 2-way banks)
#pragma unroll
        for (int dt = 0; dt < 5; ++dt) {
            int vr = dt * 16 + l16; if (vr > 71) vr = 71;   // pad lanes discarded
            const bf16* vb = &Vs[b][vr * 64];
            const short8 bv0 = *(const short8*)(vb + ((quad ^ (vr & 7)) * 8));
            const short8 bv1 = *(const short8*)(vb + (((quad + 4) ^ (vr & 7)) * 8));
            oacc[dt] = MFMA16(ap0, bv0, oacc[dt]);
            oacc[dt] = MFMA16(ap1, bv1, oacc[dt]);
        }
    }

    // epilogue: AO[t][h*72+d] = O / l
#pragma unroll
    for (int r = 0; r < 4; ++r) {
        const int qrow = q0 + wave * 16 + quad * 4 + r;
        if (qrow < seq_end) {
            const float inv = (l_i[r] > 0.f) ? (1.0f / l_i[r]) : 0.f;
#pragma unroll
            for (int d = 0; d < 5; ++d) {
                const int dim = d * 16 + l16;
                if (dim < 72)
                    AO[(size_t)qrow * 1152 + h * 72 + dim] =
                        __float2bfloat16(oacc[d][r] * inv);
            }
        }
    }
}

extern "C" void kernel_launch(void* const* d_in, const int* in_sizes, int n_in,
                              void* d_out, int out_size, void* d_ws, size_t ws_size,
                              hipStream_t stream)
{
    const float* Xf   = (const float*)d_in[0];
    const float* Wqkv = (const float*)d_in[1];
    const float* Bqkv = (const float*)d_in[2];
    const float* Wout = (const float*)d_in[3];
    const float* Bout = (const float*)d_in[4];
    const int*   cu   = (const int*)d_in[5];

    const size_t X16_B  = (size_t)4096 * 1152 * 2;
    const size_t WQ16_B = (size_t)3456 * 1152 * 2;
    const size_t WO16_B = (size_t)1152 * 1152 * 2;
    const size_t H_B    = (size_t)16 * 4096 * 72 * 2;   // 9.44 MB each

    char* ws = (char*)d_ws;
    bf16* X16  = (bf16*)ws;
    bf16* WQ16 = (bf16*)(ws + X16_B);
    bf16* WO16 = (bf16*)(ws + X16_B + WQ16_B);
    bf16* Qh   = (bf16*)(ws + X16_B + WQ16_B + WO16_B);
    bf16* Kh   = (bf16*)(ws + X16_B + WQ16_B + WO16_B + H_B);
    bf16* Vt   = (bf16*)(ws + X16_B + WQ16_B + WO16_B + 2 * H_B);
    bf16* AO   = (bf16*)(ws + X16_B + WQ16_B + WO16_B + 3 * H_B);
    float* Out = (float*)d_out;

    dim3 blk(256);
    cvt_all<<<dim3(4896), blk, 0, stream>>>(Xf, X16, 4096 * 1152,
                                            Wqkv, WQ16, 3456 * 1152,
                                            Wout, WO16, 1152 * 1152);

    hipMemsetAsync(d_out, 0, (size_t)4096 * 1152 * 4, stream);

    // QKV projection -> Qh/Kh per-head + Vt transposed
    gemm_xwt<<<dim3(32, 27, 1), blk, 0, stream>>>(X16, WQ16, Bqkv, nullptr,
                                                  Qh, Kh, Vt, 4096, 3456, 1152, 1);
    // varlen attention: 128-row q tiles (max 39 blocks for any cu partition)
    attn_varlen<<<dim3(39, 16), dim3(512), 0, stream>>>(Qh, Kh, Vt, cu, AO);
    // output projection, split-K=2
    gemm_xwt<<<dim3(32, 9, 2), blk, 0, stream>>>(AO, WO16, Bout, Out,
                                                 nullptr, nullptr, nullptr,
                                                 4096, 1152, 1152, 0);
}